// Round 2
// baseline (837.311 us; speedup 1.0000x reference)
//
#include <hip/hip_runtime.h>
#include <cmath>

#define N_NODES   100000
#define N_EDGES   3200000
#define D_FEAT    512
#define HIDDEN    16
#define N_CLASSES 7

#define NCHUNK 250                   // pass-1 blocks of 1024 thr; 250*12800 = 3.2M exactly
#define CHUNK  12800
#define NBKT   1563                  // buckets of 64 nodes (dst>>6)

typedef __attribute__((ext_vector_type(4))) float  f32x4;
typedef __attribute__((ext_vector_type(8))) short  bf16x8;

__device__ __forceinline__ short f2bf(float f) {
    union { float f; unsigned u; } v; v.f = f;
    unsigned r = v.u + 0x7fffu + ((v.u >> 16) & 1u);   // RNE
    return (short)(r >> 16);
}
__device__ __forceinline__ float bf2f(unsigned short s) {
    union { unsigned u; float f; } v; v.u = ((unsigned)s) << 16;
    return v.f;
}

// ---------------- pass 1a: per-chunk LDS hist -> global bucket counts ------
__global__ __launch_bounds__(1024) void k_hist(const int* __restrict__ dst,
                                               unsigned* __restrict__ bucket_count) {
    __shared__ unsigned h[NBKT];
    int t = threadIdx.x, b = blockIdx.x;
    for (int i = t; i < NBKT; i += 1024) h[i] = 0u;
    __syncthreads();
    int base = b * CHUNK;
    #pragma unroll 2
    for (int k = 0; k < 13; ++k) {
        int idx = k * 1024 + t;
        if (idx < CHUNK) atomicAdd(&h[((unsigned)dst[base + idx]) >> 6], 1u);
    }
    __syncthreads();
    for (int i = t; i < NBKT; i += 1024) {
        unsigned v = h[i];
        if (v) atomicAdd(&bucket_count[i], v);
    }
}

// -------- scan: exclusive scan of 1563 bucket totals (single block) --------
__global__ __launch_bounds__(256) void k_scan(const unsigned* __restrict__ bucket_count,
                                              unsigned* __restrict__ bin_base,
                                              unsigned* __restrict__ bin_cursor) {
    __shared__ unsigned t0[256];
    int t = threadIdx.x;
    unsigned running = 0u;
    for (int c0 = 0; c0 < NBKT; c0 += 256) {
        int i = c0 + t;
        unsigned v = (i < NBKT) ? bucket_count[i] : 0u;
        t0[t] = v; __syncthreads();
        #pragma unroll
        for (int off = 1; off < 256; off <<= 1) {
            unsigned add = (t >= off) ? t0[t - off] : 0u;
            __syncthreads();
            t0[t] += add;
            __syncthreads();
        }
        if (i < NBKT) {
            unsigned e = running + t0[t] - v;
            bin_base[i]   = e;
            bin_cursor[i] = e;
        }
        unsigned chunk_sum = t0[255];
        __syncthreads();          // protect t0 before next-iteration overwrite
        running += chunk_sum;
    }
    if (t == 0) bin_base[NBKT] = running;   // == N_EDGES
}

// ---------------- pass 1b: reserve ranges + scatter packed edges -----------
// packed word = (dst & 63) << 24 | src    (src < 100000 < 2^24)
__global__ __launch_bounds__(1024) void k_scatter(const int* __restrict__ src,
                                                  const int* __restrict__ dst,
                                                  unsigned* __restrict__ bin_cursor,
                                                  unsigned* __restrict__ packed) {
    __shared__ unsigned h[NBKT];
    int t = threadIdx.x, b = blockIdx.x;
    for (int i = t; i < NBKT; i += 1024) h[i] = 0u;
    __syncthreads();
    int base = b * CHUNK;
    #pragma unroll 2
    for (int k = 0; k < 13; ++k) {
        int idx = k * 1024 + t;
        if (idx < CHUNK) atomicAdd(&h[((unsigned)dst[base + idx]) >> 6], 1u);
    }
    __syncthreads();
    for (int i = t; i < NBKT; i += 1024) {
        unsigned c = h[i];
        h[i] = c ? atomicAdd(&bin_cursor[i], c) : 0u;
    }
    __syncthreads();
    #pragma unroll 2
    for (int k = 0; k < 13; ++k) {
        int idx = k * 1024 + t;
        if (idx < CHUNK) {
            int e = base + idx;
            unsigned d = (unsigned)dst[e];
            unsigned pos = atomicAdd(&h[d >> 6], 1u);   // LDS atomic
            packed[pos] = ((d & 63u) << 24) | (unsigned)src[e];
        }
    }
}

// -------- per-bucket degree count -> dinv (no sort, no csr) ----------------
__global__ __launch_bounds__(256) void k_deg(const unsigned* __restrict__ packed,
                                             const unsigned* __restrict__ bin_base,
                                             float* __restrict__ dinv) {
    __shared__ unsigned hh[4][64];
    int t = threadIdx.x, b = blockIdx.x;
    int w = t >> 6, l = t & 63;
    unsigned rs = bin_base[b], re = bin_base[b + 1];
    hh[w][l] = 0u;
    __syncthreads();
    for (unsigned i = rs + t; i < re; i += 256)
        atomicAdd(&hh[w][packed[i] >> 24], 1u);
    __syncthreads();
    if (t < 64) {
        int node = b * 64 + t;
        if (node < N_NODES) {
            unsigned total = hh[0][t] + hh[1][t] + hh[2][t] + hh[3][t];
            dinv[node] = rsqrtf((float)(total + 1u));   // +1 self loop
        }
    }
}

// ------- GEMM1: h1p = bf16( dinv .* (x@W1) )  (bf16 MFMA, fp32 acc) --------
__global__ __launch_bounds__(256) void k_gemm1(const float* __restrict__ x,
                                               const float* __restrict__ w1,
                                               const float* __restrict__ dinv,
                                               unsigned short* __restrict__ h1p) {
    __shared__ __align__(16) short w1t[16][520];
    int tid = threadIdx.x;
    for (int idx = tid; idx < D_FEAT * HIDDEN; idx += 256) {
        int k = idx >> 4, n = idx & 15;
        w1t[n][k] = f2bf(w1[idx]);
    }
    __syncthreads();

    int lane = tid & 63, wid = tid >> 6;
    int m  = lane & 15;
    int kg = lane >> 4;

    bf16x8 bfrag[16];
    #pragma unroll
    for (int ks = 0; ks < 16; ++ks)
        bfrag[ks] = *(const bf16x8*)&w1t[m][ks * 32 + kg * 8];

    int tile = blockIdx.x * 4 + wid;
    if (tile >= (N_NODES / 16)) return;

    const f32x4* xr = (const f32x4*)(x + (size_t)(tile * 16 + m) * D_FEAT);
    f32x4 acc = {0.f, 0.f, 0.f, 0.f};
    #pragma unroll
    for (int ks = 0; ks < 16; ++ks) {
        f32x4 x0 = xr[ks * 8 + kg * 2];
        f32x4 x1 = xr[ks * 8 + kg * 2 + 1];
        bf16x8 a;
        a[0] = f2bf(x0[0]); a[1] = f2bf(x0[1]); a[2] = f2bf(x0[2]); a[3] = f2bf(x0[3]);
        a[4] = f2bf(x1[0]); a[5] = f2bf(x1[1]); a[6] = f2bf(x1[2]); a[7] = f2bf(x1[3]);
        acc = __builtin_amdgcn_mfma_f32_16x16x32_bf16(a, bfrag[ks], acc, 0, 0, 0);
    }
    // C layout: col = lane&15, row = (lane>>4)*4 + reg  [m89-verified]
    size_t base = (size_t)tile * 256;
    #pragma unroll
    for (int r = 0; r < 4; ++r) {
        int rr = kg * 4 + r;
        h1p[base + rr * 16 + m] = (unsigned short)f2bf(dinv[tile * 16 + rr] * acc[r]);
    }
}

// ------- bucket-parallel gather layer 1 + layer-2 transform ----------------
// One block per 64-node bucket; 16 lanes per edge; LDS f32 accumulators.
__global__ __launch_bounds__(256) void k_gatherA(const unsigned* __restrict__ packed,
                                                 const unsigned* __restrict__ bin_base,
                                                 const unsigned short* __restrict__ h1p,
                                                 const float* __restrict__ dinv,
                                                 const float* __restrict__ w2,
                                                 const float* __restrict__ b1,
                                                 float* __restrict__ h2p) {
    __shared__ float acc[64][17];       // +1 pad: spreads atomic banks
    __shared__ float w2s[16][8];
    __shared__ float b1s[16];
    int t = threadIdx.x, b = blockIdx.x;
    if (t < 128) { int jj = t >> 3, c = t & 7;
                   w2s[jj][c] = (c < N_CLASSES) ? w2[jj * N_CLASSES + c] : 0.f; }
    if (t < 16) b1s[t] = b1[t];
    // init accumulators with the self term
    #pragma unroll
    for (int k = 0; k < 4; ++k) {
        int e = t + k * 256;            // 0..1023
        int l = e >> 4, j = e & 15;
        int node = b * 64 + l;
        acc[l][j] = (node < N_NODES) ? bf2f(h1p[(size_t)node * 16 + j]) : 0.f;
    }
    unsigned rs = bin_base[b], re = bin_base[b + 1];
    __syncthreads();
    int slot = t >> 4, j = t & 15;      // 16 edges per block-iteration
    #pragma unroll 2
    for (unsigned i0 = rs; i0 < re; i0 += 16) {
        unsigned idx = i0 + (unsigned)slot;
        if (idx < re) {
            unsigned p = packed[idx];
            float v = bf2f(h1p[(size_t)(p & 0xFFFFFFu) * 16 + j]);
            atomicAdd(&acc[p >> 24][j], v);
        }
    }
    __syncthreads();
    if (t < 64) {
        int node = b * 64 + t;
        if (node < N_NODES) {
            float di = dinv[node];
            float h[16];
            #pragma unroll
            for (int jj = 0; jj < 16; ++jj)
                h[jj] = fmaxf(fmaf(di, acc[t][jj], b1s[jj]), 0.f);
            float* h2r = h2p + (size_t)node * 8;
            #pragma unroll
            for (int c = 0; c < N_CLASSES; ++c) {
                float o = 0.f;
                #pragma unroll
                for (int jj = 0; jj < 16; ++jj) o = fmaf(h[jj], w2s[jj][c], o);
                h2r[c] = di * o;
            }
            h2r[7] = 0.f;
        }
    }
}

// ------- bucket-parallel gather layer 2 + bias + log_softmax ---------------
// One block per bucket; 8 lanes per edge; LDS accumulators.
__global__ __launch_bounds__(256) void k_gatherB(const unsigned* __restrict__ packed,
                                                 const unsigned* __restrict__ bin_base,
                                                 const float* __restrict__ h2p,
                                                 const float* __restrict__ dinv,
                                                 const float* __restrict__ b2,
                                                 float* __restrict__ out) {
    __shared__ float acc[64][9];        // +1 pad
    int t = threadIdx.x, b = blockIdx.x;
    #pragma unroll
    for (int k = 0; k < 2; ++k) {
        int e = t + k * 256;            // 0..511
        int l = e >> 3, c = e & 7;
        int node = b * 64 + l;
        acc[l][c] = (node < N_NODES) ? h2p[(size_t)node * 8 + c] : 0.f;  // self
    }
    unsigned rs = bin_base[b], re = bin_base[b + 1];
    __syncthreads();
    int slot = t >> 3, c = t & 7;       // 32 edges per block-iteration
    #pragma unroll 2
    for (unsigned i0 = rs; i0 < re; i0 += 32) {
        unsigned idx = i0 + (unsigned)slot;
        if (idx < re) {
            unsigned p = packed[idx];
            float v = h2p[(size_t)(p & 0xFFFFFFu) * 8 + c];
            atomicAdd(&acc[p >> 24][c], v);
        }
    }
    __syncthreads();
    if (t < 64) {
        int node = b * 64 + t;
        if (node < N_NODES) {
            float di = dinv[node];
            float lg[N_CLASSES];
            float mx = -1e30f;
            #pragma unroll
            for (int cc = 0; cc < N_CLASSES; ++cc) {
                lg[cc] = fmaf(di, acc[t][cc], b2[cc]);
                mx = fmaxf(mx, lg[cc]);
            }
            float sum = 0.f;
            #pragma unroll
            for (int cc = 0; cc < N_CLASSES; ++cc) sum += __expf(lg[cc] - mx);
            float lse = mx + __logf(sum);
            float* orow = out + (size_t)node * N_CLASSES;
            #pragma unroll
            for (int cc = 0; cc < N_CLASSES; ++cc) orow[cc] = lg[cc] - lse;
        }
    }
}

extern "C" void kernel_launch(void* const* d_in, const int* in_sizes, int n_in,
                              void* d_out, int out_size, void* d_ws, size_t ws_size,
                              hipStream_t stream) {
    const float* x  = (const float*)d_in[0];
    const int*   ei = (const int*)d_in[1];
    const float* w1 = (const float*)d_in[2];
    const float* b1 = (const float*)d_in[3];
    const float* w2 = (const float*)d_in[4];
    const float* b2 = (const float*)d_in[5];
    float* out = (float*)d_out;

    const int* src = ei;
    const int* dst = ei + N_EDGES;

    // workspace carve (u32 units), ~24 MB
    unsigned* w32            = (unsigned*)d_ws;
    float*    dinv           = (float*)(w32 + 0);                   // 102,400
    unsigned short* h1p      = (unsigned short*)(w32 + 102400);     // 1.6M ushort = 800,000 u32
    float*    h2p            = (float*)(w32 + 902400);              //   800,000
    unsigned* bucket_count   = w32 + 1702400;                       // 2,048
    unsigned* bin_base       = w32 + 1704448;                       // 2,048 (need NBKT+1)
    unsigned* bin_cursor     = w32 + 1706496;                       // 2,048
    unsigned* packed         = w32 + 1708544;                       // 3,200,000

    const int GB = (N_NODES / 16 + 3) / 4;             // 1563 gemm blocks

    hipMemsetAsync(bucket_count, 0, NBKT * sizeof(unsigned), stream);
    k_hist    <<<NCHUNK, 1024, 0, stream>>>(dst, bucket_count);
    k_scan    <<<1,      256,  0, stream>>>(bucket_count, bin_base, bin_cursor);
    k_scatter <<<NCHUNK, 1024, 0, stream>>>(src, dst, bin_cursor, packed);
    k_deg     <<<NBKT,   256,  0, stream>>>(packed, bin_base, dinv);
    k_gemm1   <<<GB,     256,  0, stream>>>(x, w1, dinv, h1p);
    k_gatherA <<<NBKT,   256,  0, stream>>>(packed, bin_base, h1p, dinv, w2, b1, h2p);
    k_gatherB <<<NBKT,   256,  0, stream>>>(packed, bin_base, h2p, dinv, b2, out);
}

// Round 4
// 487.384 us; speedup vs baseline: 1.7180x; 1.7180x over previous
//
#include <hip/hip_runtime.h>
#include <cmath>

#define N_NODES   100000
#define N_EDGES   3200000
#define D_FEAT    512
#define HIDDEN    16
#define N_CLASSES 7

#define NCHUNK 250                   // scatter blocks of 1024 thr; 250*12800 = 3.2M exactly
#define CHUNK  12800
#define NBKT   1563                  // buckets of 64 nodes (dst>>6)
#define BCAP   2560                  // fixed bucket capacity; mean 2048, sigma 45 -> 11 sigma slack

typedef __attribute__((ext_vector_type(4))) float  f32x4;
typedef __attribute__((ext_vector_type(8))) short  bf16x8;

__device__ __forceinline__ short f2bf(float f) {
    union { float f; unsigned u; } v; v.f = f;
    unsigned r = v.u + 0x7fffu + ((v.u >> 16) & 1u);   // RNE
    return (short)(r >> 16);
}
__device__ __forceinline__ float bf2f(unsigned short s) {
    union { unsigned u; float f; } v; v.u = ((unsigned)s) << 16;
    return v.f;
}

// ---- pass 1: per-chunk LDS hist -> reserve fixed-stride slices -> scatter --
// packed word = (dst & 63) << 24 | src    (src < 100000 < 2^24)
// bucket b's edges live at packed[b*BCAP .. b*BCAP + cnt[b])
__global__ __launch_bounds__(1024) void k_scatterD(const int* __restrict__ src,
                                                   const int* __restrict__ dst,
                                                   unsigned* __restrict__ cnt,
                                                   unsigned* __restrict__ packed) {
    __shared__ unsigned h[NBKT];
    int t = threadIdx.x, b = blockIdx.x;
    for (int i = t; i < NBKT; i += 1024) h[i] = 0u;
    __syncthreads();
    int base = b * CHUNK;
    // phase a: local histogram (dst slice stays hot in L1/L2 for phase c)
    #pragma unroll 2
    for (int k = 0; k < 13; ++k) {
        int idx = k * 1024 + t;
        if (idx < CHUNK) atomicAdd(&h[((unsigned)dst[base + idx]) >> 6], 1u);
    }
    __syncthreads();
    // phase b: reserve a contiguous slice of each bucket for this block
    for (int i = t; i < NBKT; i += 1024) {
        unsigned c = h[i];
        h[i] = c ? ((unsigned)i * BCAP + atomicAdd(&cnt[i], c)) : 0u;
    }
    __syncthreads();
    // phase c: scatter into reserved slices via LDS cursors
    #pragma unroll 2
    for (int k = 0; k < 13; ++k) {
        int idx = k * 1024 + t;
        if (idx < CHUNK) {
            int e = base + idx;
            unsigned d = (unsigned)dst[e];
            unsigned pos = atomicAdd(&h[d >> 6], 1u);   // LDS atomic
            packed[pos] = ((d & 63u) << 24) | (unsigned)src[e];
        }
    }
}

// -------- pass 2: per-bucket exact-dst sort -> deg, row_start, dinv, csr ---
__global__ __launch_bounds__(256) void k_bucket(const unsigned* __restrict__ packed,
                                                const unsigned* __restrict__ cnt,
                                                unsigned* __restrict__ deg,
                                                unsigned* __restrict__ row_start,
                                                float* __restrict__ dinv,
                                                int* __restrict__ csr_src) {
    __shared__ unsigned hh[4][64], sc[64], cur[64];
    int t = threadIdx.x, b = blockIdx.x;
    int w = t >> 6, l = t & 63;
    unsigned rs = (unsigned)b * BCAP;
    unsigned re = rs + cnt[b];
    hh[w][l] = 0u;
    __syncthreads();
    for (unsigned i = rs + t; i < re; i += 256)
        atomicAdd(&hh[w][packed[i] >> 24], 1u);    // per-wave sub-hist
    __syncthreads();
    unsigned total = 0u;
    if (t < 64) {
        total = hh[0][t] + hh[1][t] + hh[2][t] + hh[3][t];
        sc[t] = total;
    }
    __syncthreads();
    #pragma unroll
    for (int off = 1; off < 64; off <<= 1) {
        unsigned add = (t >= off && t < 64) ? sc[t - off] : 0u;
        __syncthreads();
        if (t < 64) sc[t] += add;
        __syncthreads();
    }
    if (t < 64) {
        unsigned excl = sc[t] - total;
        int node = b * 64 + t;
        if (node < N_NODES) {
            deg[node]       = total;
            row_start[node] = rs + excl;
            dinv[node]      = rsqrtf((float)(total + 1u));
        }
        cur[t] = rs + excl;
    }
    __syncthreads();
    for (unsigned i = rs + t; i < re; i += 256) {
        unsigned p = packed[i];
        unsigned pos = atomicAdd(&cur[p >> 24], 1u);     // LDS atomic
        csr_src[pos] = (int)(p & 0xFFFFFFu);
    }
}

// ------- GEMM1: h1p = bf16( dinv .* (x@W1) )  (bf16 MFMA, fp32 acc) --------
__global__ __launch_bounds__(256) void k_gemm1(const float* __restrict__ x,
                                               const float* __restrict__ w1,
                                               const float* __restrict__ dinv,
                                               unsigned short* __restrict__ h1p) {
    __shared__ __align__(16) short w1t[16][520];
    int tid = threadIdx.x;
    for (int idx = tid; idx < D_FEAT * HIDDEN; idx += 256) {
        int k = idx >> 4, n = idx & 15;
        w1t[n][k] = f2bf(w1[idx]);
    }
    __syncthreads();

    int lane = tid & 63, wid = tid >> 6;
    int m  = lane & 15;
    int kg = lane >> 4;

    bf16x8 bfrag[16];
    #pragma unroll
    for (int ks = 0; ks < 16; ++ks)
        bfrag[ks] = *(const bf16x8*)&w1t[m][ks * 32 + kg * 8];

    int tile = blockIdx.x * 4 + wid;
    if (tile >= (N_NODES / 16)) return;

    const f32x4* xr = (const f32x4*)(x + (size_t)(tile * 16 + m) * D_FEAT);
    f32x4 acc = {0.f, 0.f, 0.f, 0.f};
    #pragma unroll
    for (int ks = 0; ks < 16; ++ks) {
        f32x4 x0 = xr[ks * 8 + kg * 2];
        f32x4 x1 = xr[ks * 8 + kg * 2 + 1];
        bf16x8 a;
        a[0] = f2bf(x0[0]); a[1] = f2bf(x0[1]); a[2] = f2bf(x0[2]); a[3] = f2bf(x0[3]);
        a[4] = f2bf(x1[0]); a[5] = f2bf(x1[1]); a[6] = f2bf(x1[2]); a[7] = f2bf(x1[3]);
        acc = __builtin_amdgcn_mfma_f32_16x16x32_bf16(a, bfrag[ks], acc, 0, 0, 0);
    }
    // C layout: col = lane&15, row = (lane>>4)*4 + reg  [m89-verified]
    size_t base = (size_t)tile * 256;
    #pragma unroll
    for (int r = 0; r < 4; ++r) {
        int rr = kg * 4 + r;
        h1p[base + rr * 16 + m] = (unsigned short)f2bf(dinv[tile * 16 + rr] * acc[r]);
    }
}

// ------- gather layer 1 FUSED with layer 2 ---------------------------------
// g1[i][j] = h1p[i][j] + sum_e h1p[src_e][j]   (lanes 0..15 hold j after reduce)
// then h[j] = relu(dinv*g1 + b1);  h2p[i][c] = dinv * sum_j h[j]*W2[j][c]
__global__ __launch_bounds__(256) void k_gather1(const int* __restrict__ csr_src,
                                                 const unsigned* __restrict__ row_start,
                                                 const unsigned* __restrict__ deg,
                                                 const unsigned short* __restrict__ h1p,
                                                 const float* __restrict__ dinv,
                                                 const float* __restrict__ w2,
                                                 const float* __restrict__ b1,
                                                 float* __restrict__ h2p) {
    __shared__ float w2s[16][8];
    __shared__ float b1s[16];
    int tid  = threadIdx.x;
    if (tid < 128) {
        int jj = tid >> 3, c = tid & 7;
        w2s[jj][c] = (c < N_CLASSES) ? w2[jj * N_CLASSES + c] : 0.f;
    }
    if (tid < 16) b1s[tid] = b1[tid];
    __syncthreads();

    int lane = tid & 63;
    int node = blockIdx.x * 4 + (tid >> 6);
    int j  = lane & 15;
    int sl = lane >> 4;          // 0..3

    unsigned start = row_start[node];
    unsigned end   = start + deg[node];

    float acc = (sl == 0) ? bf2f(h1p[(size_t)node * 16 + j]) : 0.f;   // self term
    unsigned e = start;
    for (; e + 16 <= end; e += 16) {
        int s0 = csr_src[e      + sl];
        int s1 = csr_src[e + 4  + sl];
        int s2 = csr_src[e + 8  + sl];
        int s3 = csr_src[e + 12 + sl];
        float v0 = bf2f(h1p[(size_t)s0 * 16 + j]);
        float v1 = bf2f(h1p[(size_t)s1 * 16 + j]);
        float v2 = bf2f(h1p[(size_t)s2 * 16 + j]);
        float v3 = bf2f(h1p[(size_t)s3 * 16 + j]);
        acc += v0; acc += v1; acc += v2; acc += v3;
    }
    for (; e < end; e += 4) {
        unsigned idx = e + (unsigned)sl;
        float v = 0.f;
        if (idx < end) v = bf2f(h1p[(size_t)csr_src[idx] * 16 + j]);
        acc += v;
    }
    acc += __shfl_down(acc, 32);
    acc += __shfl_down(acc, 16);
    // lanes 0..15 (sl==0, lane==j) now hold the full g1 row

    float di = dinv[node];
    float hv = fmaxf(fmaf(di, acc, b1s[j]), 0.f);     // valid on lanes 0..15
    float o = 0.f;
    int c = lane & 7;
    #pragma unroll
    for (int jj = 0; jj < 16; ++jj)
        o = fmaf(__shfl(hv, jj), w2s[jj][c], o);
    if (lane < 8)
        h2p[(size_t)node * 8 + c] = (c < N_CLASSES) ? di * o : 0.f;
}

// ------- gather layer 2 + bias + log_softmax fused -------------------------
__global__ __launch_bounds__(256) void k_gather2(const int* __restrict__ csr_src,
                                                 const unsigned* __restrict__ row_start,
                                                 const unsigned* __restrict__ deg,
                                                 const float* __restrict__ dinv,
                                                 const float* __restrict__ h2p,
                                                 const float* __restrict__ b2,
                                                 float* __restrict__ out) {
    int tid  = threadIdx.x;
    int lane = tid & 63;
    int node = blockIdx.x * 4 + (tid >> 6);
    int j  = lane & 7;
    int sl = lane >> 3;          // 0..7

    unsigned start = row_start[node];
    unsigned end   = start + deg[node];

    float acc = (sl == 0) ? h2p[(size_t)node * 8 + j] : 0.f;    // self term
    unsigned e = start;
    for (; e + 32 <= end; e += 32) {
        int s0 = csr_src[e      + sl];
        int s1 = csr_src[e + 8  + sl];
        int s2 = csr_src[e + 16 + sl];
        int s3 = csr_src[e + 24 + sl];
        float v0 = h2p[(size_t)s0 * 8 + j];
        float v1 = h2p[(size_t)s1 * 8 + j];
        float v2 = h2p[(size_t)s2 * 8 + j];
        float v3 = h2p[(size_t)s3 * 8 + j];
        acc += v0; acc += v1; acc += v2; acc += v3;
    }
    for (; e < end; e += 8) {
        unsigned idx = e + (unsigned)sl;
        float v = 0.f;
        if (idx < end) v = h2p[(size_t)csr_src[idx] * 8 + j];
        acc += v;
    }
    acc += __shfl_down(acc, 32);
    acc += __shfl_down(acc, 16);
    acc += __shfl_down(acc, 8);
    float di = dinv[node];
    float logit = (j < N_CLASSES) ? di * acc + b2[j] : -1e30f;
    float mx = logit;
    #pragma unroll
    for (int mk = 1; mk < 8; mk <<= 1) mx = fmaxf(mx, __shfl_xor(mx, mk, 8));
    float ex = (j < N_CLASSES) ? __expf(logit - mx) : 0.f;
    float sum = ex;
    #pragma unroll
    for (int mk = 1; mk < 8; mk <<= 1) sum += __shfl_xor(sum, mk, 8);
    if (sl == 0 && j < N_CLASSES)
        out[(size_t)node * N_CLASSES + j] = logit - mx - __logf(sum);
}

extern "C" void kernel_launch(void* const* d_in, const int* in_sizes, int n_in,
                              void* d_out, int out_size, void* d_ws, size_t ws_size,
                              hipStream_t stream) {
    const float* x  = (const float*)d_in[0];
    const int*   ei = (const int*)d_in[1];
    const float* w1 = (const float*)d_in[2];
    const float* b1 = (const float*)d_in[3];
    const float* w2 = (const float*)d_in[4];
    const float* b2 = (const float*)d_in[5];
    float* out = (float*)d_out;

    const int* src = ei;
    const int* dst = ei + N_EDGES;

    // workspace carve (u32 units), ~40 MB
    unsigned* w32            = (unsigned*)d_ws;
    float*    dinv           = (float*)(w32 + 0);                   // 102,400
    unsigned short* h1p      = (unsigned short*)(w32 + 102400);     // 1.6M ushort = 800,000 u32
    float*    h2p            = (float*)(w32 + 902400);              //   800,000
    unsigned* deg            = w32 + 1702400;                       // 102,400
    unsigned* row_start      = w32 + 1804800;                       // 102,400
    unsigned* cnt            = w32 + 1907200;                       // 2,048
    unsigned* packed         = w32 + 1909248;                       // 4,001,280 (NBKT*BCAP)
    int*      csr_src        = (int*)(w32 + 5910528);               // 4,001,280

    const int GB = (N_NODES / 16 + 3) / 4;             // 1563 gemm blocks

    hipMemsetAsync(cnt, 0, NBKT * sizeof(unsigned), stream);
    k_scatterD<<<NCHUNK, 1024, 0, stream>>>(src, dst, cnt, packed);
    k_bucket  <<<NBKT,   256,  0, stream>>>(packed, cnt, deg, row_start, dinv, csr_src);
    k_gemm1   <<<GB,     256,  0, stream>>>(x, w1, dinv, h1p);
    k_gather1 <<<25000,  256,  0, stream>>>(csr_src, row_start, deg, h1p, dinv, w2, b1, h2p);
    k_gather2 <<<25000,  256,  0, stream>>>(csr_src, row_start, deg, dinv, h2p, b2, out);
}